// Round 7
// baseline (253.475 us; speedup 1.0000x reference)
//
#include <hip/hip_runtime.h>
#include <hip/hip_bf16.h>

#define B_  16
#define LQ  2048
#define LS  2048
#define DD  512
#define BQ  256
#define BS  256
#define BK  32
#define NSB (LS / BS)    // 8 s-blocks total
#define NKC (DD / BK)    // 16 k-stages per s-block
#define NSPLIT 2
#define T_STAGES ((NSB / NSPLIT) * NKC)   // 64

typedef short bf16x8 __attribute__((ext_vector_type(8)));
typedef float f32x4  __attribute__((ext_vector_type(4)));
typedef unsigned short u16x8 __attribute__((ext_vector_type(8)));

// async global->LDS, 16B per lane. LDS dest = wave-uniform base + lane*16.
__device__ __forceinline__ void load_lds16(const void* g, void* l) {
  __builtin_amdgcn_global_load_lds((const __attribute__((address_space(1))) void*)g,
                                   (__attribute__((address_space(3))) void*)l,
                                   16, 0, 0);
}

__device__ __forceinline__ unsigned short f2bf(float f) {
  union { float f; unsigned int u; } v; v.f = f;
  unsigned int r = v.u + 0x7fffu + ((v.u >> 16) & 1u);  // RNE
  return (unsigned short)(r >> 16);
}

// 8 elems/thread: 2 float4 reads -> one 16B store.
__global__ __launch_bounds__(256) void cvt_kernel(const float* __restrict__ Q,
                                                  const float* __restrict__ S,
                                                  unsigned short* __restrict__ Qw,
                                                  unsigned short* __restrict__ Sw,
                                                  int nblk) {
  int blk = blockIdx.x;
  const float* src; unsigned short* dst;
  if (blk < nblk) { src = Q; dst = Qw; } else { src = S; dst = Sw; blk -= nblk; }
  int i = blk * 256 + threadIdx.x;   // 8-elem index
  float4 f0 = ((const float4*)src)[i * 2];
  float4 f1 = ((const float4*)src)[i * 2 + 1];
  u16x8 u;
  u[0] = f2bf(f0.x); u[1] = f2bf(f0.y); u[2] = f2bf(f0.z); u[3] = f2bf(f0.w);
  u[4] = f2bf(f1.x); u[5] = f2bf(f1.y); u[6] = f2bf(f1.z); u[7] = f2bf(f1.w);
  ((u16x8*)dst)[i] = u;
}

// score[b,q] = sum_s softmax(l)[s]*l[s],  l[s] = Q[b,q,:].S[b,s,:]
// MFMA: A = S-tile (M=s), B = Q-tile^T (N=q) -> C[row=s][col=q]
// C layout (16x16x32): col = lane&15, row = (lane>>4)*4 + reg  [m89/m91]
//
// Round-7: r6 audit showed LDS-port-bound with convoy: 128 KB fragment
// reads/stage/CU at 85 B/cyc + MFMA phase serialized. LDS bytes per FLOP are
// set ONLY by the wave tile: FLOP/B = Ms*Nq/(Ms+Nq). Grow wave tile to
// 64s x 128q (32 -> 42.7 FLOP/B) and halve waves to 8 (512 thr, 2/SIMD,
// __launch_bounds__(512,2) to cap 256 VGPR: acc 128 + frags 48 + addr ~35).
// Per stage/CU: 96 KB reads + 32 KB DMA write ~1.5k cyc, MFMA 1.24k cyc.
// Keep: ring-4 LDS (4 x 32 KB), precise s_waitcnt vmcnt + raw s_barrier
// (1 barrier/stage), ghost-clamped tail, conflict-free XOR swizzle
// (chunk c of row r stored at pos c^(r&3)^((r>>2)&3); uniform 8/bank).
__global__ __launch_bounds__(512, 2) void attn_kernel(const unsigned short* __restrict__ Qw,
                                                      const unsigned short* __restrict__ Sw,
                                                      float* __restrict__ pm,
                                                      float* __restrict__ pse,
                                                      float* __restrict__ psel) {
  __shared__ __align__(16) unsigned short sQ0[BQ * BK], sS0[BS * BK];  // 16+16 KiB
  __shared__ __align__(16) unsigned short sQ1[BQ * BK], sS1[BS * BK];
  __shared__ __align__(16) unsigned short sQ2[BQ * BK], sS2[BS * BK];
  __shared__ __align__(16) unsigned short sQ3[BQ * BK], sS3[BS * BK];  // 128 KiB total

  const int id   = blockIdx.x;
  const int qb   = id >> 5;       // 0..7
  const int bsx  = id & 31;
  const int b    = bsx >> 1;      // 0..15  (XCD swizzle: id%8 groups share S-half)
  const int spl  = bsx & 1;
  const int tid  = threadIdx.x;
  const int w    = tid >> 6;      // 0..7
  const int lane = tid & 63;
  const int h    = w & 3;         // s-quarter: rows [h*64, +64)
  const int g    = w >> 2;        // q-half:    cols [g*128, +128)
  const int col  = lane & 15;
  const int quad = lane >> 4;

  const int q0 = qb * BQ;
  const unsigned short* Qb = Qw + (size_t)b * LQ * DD;
  const unsigned short* Sb = Sw + (size_t)b * LS * DD;

  float mst[8], se[8], sel[8];
#pragma unroll
  for (int qt = 0; qt < 8; ++qt) { mst[qt] = -INFINITY; se[qt] = 0.f; sel[qt] = 0.f; }
  f32x4 acc[4][8];   // [s-tile][q-tile] = 128 VGPRs

  // staging: wave w covers sQ row-groups {2w, 2w+1} and sS row-groups
  // {2w, 2w+1} (16 rows each). lane -> row base+ (lane>>2), pos lane&3,
  // fetches global chunk (lane&3)^((lane>>2)&3)  [(r>>2)&3 term folded in
  // per-group below].
  const int rsub   = lane >> 2;               // 0..15 row within group
  const int ldsoff = lane * 8;                // elements (lane*16B)

  const int sbs = spl * (NSB / NSPLIT);

  auto issue = [&](int t, unsigned short* bq, unsigned short* bss) {
    const int ts = t < T_STAGES ? t : T_STAGES - 1;   // ghost-clamp (uniform vmcnt)
    const int kbase = (ts & 15) * BK;
    const int s0 = (sbs + (ts >> 4)) * BS;
#pragma unroll
    for (int j = 0; j < 2; ++j) {
      const int grp = 2 * w + j;              // 0..15
      const int row = grp * 16 + rsub;        // 0..255
      const int chunk = (lane & 3) ^ (rsub & 3) ^ ((rsub >> 2) & 3) ^ (grp & 3) ? 0 : 0; // placeholder
      (void)chunk;
      const int c = ((lane & 3) ^ (row & 3) ^ ((row >> 2) & 3)) * 8;
      load_lds16(Qb + (size_t)(q0 + row) * DD + kbase + c, bq  + grp * 512 + ldsoff - (size_t)(lane * 8) + ldsoff);
      load_lds16(Sb + (size_t)(s0 + row) * DD + kbase + c, bss + grp * 512 + ldsoff - (size_t)(lane * 8) + ldsoff);
    }
  };
  // NOTE: the lambda above must write LDS at wave-uniform base + lane*16;
  // grp*512 elements is the group base, ldsoff = lane*8 elements. The
  // expression simplifies to bq + grp*512 + ldsoff (kept explicit below).

  // fragment read position: row = base+col (base mult of 16, (base>>2)&3==0)
  const int pos = (quad ^ (col & 3) ^ ((col >> 2) & 3)) * 8;

  auto compute = [&](const unsigned short* bq, const unsigned short* bss) {
    bf16x8 asv[4], aq[8];
#pragma unroll
    for (int st = 0; st < 4; ++st)
      asv[st] = *(const bf16x8*)&bss[(h * 64 + st * 16 + col) * BK + pos];
#pragma unroll
    for (int qt = 0; qt < 8; ++qt)
      aq[qt] = *(const bf16x8*)&bq[(g * 128 + qt * 16 + col) * BK + pos];
#pragma unroll
    for (int st = 0; st < 4; ++st)
#pragma unroll
      for (int qt = 0; qt < 8; ++qt)
        acc[st][qt] = __builtin_amdgcn_mfma_f32_16x16x32_bf16(asv[st], aq[qt], acc[st][qt], 0, 0, 0);
  };

  auto initacc = [&]() {
#pragma unroll
    for (int st = 0; st < 4; ++st)
#pragma unroll
      for (int qt = 0; qt < 8; ++qt)
        acc[st][qt] = (f32x4){0.f, 0.f, 0.f, 0.f};
  };

  auto epilogue = [&]() {
#pragma unroll
    for (int qt = 0; qt < 8; ++qt) {
      float lmax = mst[qt];
#pragma unroll
      for (int st = 0; st < 4; ++st)
#pragma unroll
        for (int r = 0; r < 4; ++r)
          lmax = fmaxf(lmax, acc[st][qt][r]);
      lmax = fmaxf(lmax, __shfl_xor(lmax, 16, 64));
      lmax = fmaxf(lmax, __shfl_xor(lmax, 32, 64));
      float alpha = __expf(mst[qt] - lmax);
      float pe = 0.f, pel = 0.f;
#pragma unroll
      for (int st = 0; st < 4; ++st)
#pragma unroll
        for (int r = 0; r < 4; ++r) {
          float l = acc[st][qt][r];
          float e = __expf(l - lmax);
          pe += e;
          pel = fmaf(e, l, pel);
        }
      pe  += __shfl_xor(pe, 16, 64);  pe  += __shfl_xor(pe, 32, 64);
      pel += __shfl_xor(pel, 16, 64); pel += __shfl_xor(pel, 32, 64);
      se[qt]  = fmaf(se[qt],  alpha, pe);
      sel[qt] = fmaf(sel[qt], alpha, pel);
      mst[qt] = lmax;
    }
  };

#define ISSUE(t, BQp, BSp)                                                  \
  do {                                                                      \
    const int ts_ = (t) < T_STAGES ? (t) : T_STAGES - 1;                    \
    const int kb_ = (ts_ & 15) * BK;                                        \
    const int s0_ = (sbs + (ts_ >> 4)) * BS;                                \
    _Pragma("unroll")                                                       \
    for (int j = 0; j < 2; ++j) {                                           \
      const int grp_ = 2 * w + j;                                           \
      const int row_ = grp_ * 16 + rsub;                                    \
      const int c_ = ((lane & 3) ^ (row_ & 3) ^ ((row_ >> 2) & 3)) * 8;     \
      load_lds16(Qb + (size_t)(q0 + row_) * DD + kb_ + c_, (BQp) + grp_ * 512 + ldsoff); \
      load_lds16(Sb + (size_t)(s0_ + row_) * DD + kb_ + c_, (BSp) + grp_ * 512 + ldsoff); \
    }                                                                       \
  } while (0)

#define STEP(t, RQ, RS, WQ, WS)                                   \
  do {                                                            \
    asm volatile("s_waitcnt vmcnt(8)" ::: "memory");              \
    asm volatile("s_barrier" ::: "memory");                       \
    ISSUE((t) + 3, WQ, WS);                                       \
    if (((t) & 15) == 0) initacc();                               \
    compute(RQ, RS);                                              \
    if (((t) & 15) == 15) epilogue();                             \
  } while (0)

  ISSUE(0, sQ0, sS0);
  ISSUE(1, sQ1, sS1);
  ISSUE(2, sQ2, sS2);

  for (int tt = 0; tt < T_STAGES; tt += 4) {
    STEP(tt + 0, sQ0, sS0, sQ3, sS3);
    STEP(tt + 1, sQ1, sS1, sQ0, sS0);
    STEP(tt + 2, sQ2, sS2, sQ1, sS1);
    STEP(tt + 3, sQ3, sS3, sQ2, sS2);
  }
#undef STEP
#undef ISSUE

  // merge the 4 s-quarters per (g, qt, col) via LDS, write split partials
  __syncthreads();   // drains ghost DMA too
  float* red = (float*)&sQ0[0];   // 3 x 1024 floats = 12 KiB
  if (quad == 0) {
#pragma unroll
    for (int qt = 0; qt < 8; ++qt) {
      int idx = (((g * 4 + h) * 8) + qt) * 16 + col;
      red[idx]        = mst[qt];
      red[1024 + idx] = se[qt];
      red[2048 + idx] = sel[qt];
    }
  }
  __syncthreads();
  if (h == 0 && quad == 0) {
#pragma unroll
    for (int qt = 0; qt < 8; ++qt) {
      float M = -INFINITY;
#pragma unroll
      for (int hh = 0; hh < 4; ++hh)
        M = fmaxf(M, red[(((g * 4 + hh) * 8) + qt) * 16 + col]);
      float SE = 0.f, SEL = 0.f;
#pragma unroll
      for (int hh = 0; hh < 4; ++hh) {
        int idx = (((g * 4 + hh) * 8) + qt) * 16 + col;
        float a = __expf(red[idx] - M);
        SE  = fmaf(red[1024 + idx], a, SE);
        SEL = fmaf(red[2048 + idx], a, SEL);
      }
      size_t qi = (size_t)b * LQ + q0 + g * 128 + qt * 16 + col;
      pm[qi * NSPLIT + spl]   = M;
      pse[qi * NSPLIT + spl]  = SE;
      psel[qi * NSPLIT + spl] = SEL;
    }
  }
}

__global__ __launch_bounds__(256) void combine_kernel(const float* __restrict__ pm,
                                                      const float* __restrict__ pse,
                                                      const float* __restrict__ psel,
                                                      float* __restrict__ out) {
  int i = blockIdx.x * blockDim.x + threadIdx.x;
  if (i >= B_ * LQ) return;
  float M = -INFINITY;
#pragma unroll
  for (int s = 0; s < NSPLIT; ++s) M = fmaxf(M, pm[i * NSPLIT + s]);
  float SE = 0.f, SEL = 0.f;
#pragma unroll
  for (int s = 0; s < NSPLIT; ++s) {
    float a = __expf(pm[i * NSPLIT + s] - M);
    SE  = fmaf(pse[i * NSPLIT + s],  a, SE);
    SEL = fmaf(psel[i * NSPLIT + s], a, SEL);
  }
  out[i] = SEL / SE;
}

// fp32 fallback (correctness insurance if ws too small)
__global__ __launch_bounds__(256) void fallback_kernel(const float* __restrict__ Q,
                                                       const float* __restrict__ S,
                                                       float* __restrict__ out) {
  __shared__ float qv[DD];
  __shared__ float red[256];
  const int b = blockIdx.y, qi = blockIdx.x, tid = threadIdx.x;
  const float* qrow = Q + ((size_t)b * LQ + qi) * DD;
  for (int d = tid; d < DD; d += 256) qv[d] = qrow[d];
  __syncthreads();
  const float* Sb = S + (size_t)b * LS * DD;
  float m = -INFINITY, se = 0.f, sel = 0.f;
  for (int s = tid; s < LS; s += 256) {
    const float* srow = Sb + (size_t)s * DD;
    float dot = 0.f;
    for (int d = 0; d < DD; ++d) dot = fmaf(qv[d], srow[d], dot);
    float mn = fmaxf(m, dot);
    float a = __expf(m - mn);
    float e = __expf(dot - mn);
    se  = se * a + e;
    sel = sel * a + e * dot;
    m = mn;
  }
  red[tid] = m; __syncthreads();
  for (int o = 128; o > 0; o >>= 1) { if (tid < o) red[tid] = fmaxf(red[tid], red[tid + o]); __syncthreads(); }
  float M = red[0]; __syncthreads();
  float a = __expf(m - M); se *= a; sel *= a;
  red[tid] = se; __syncthreads();
  for (int o = 128; o > 0; o >>= 1) { if (tid < o) red[tid] += red[tid + o]; __syncthreads(); }
  float SE = red[0]; __syncthreads();
  red[tid] = sel; __syncthreads();
  for (int o = 128; o > 0; o >>= 1) { if (tid < o) red[tid] += red[tid + o]; __syncthreads(); }
  float SEL = red[0];
  if (tid == 0) out[(size_t)b * LQ + qi] = SEL / SE;
}

extern "C" void kernel_launch(void* const* d_in, const int* in_sizes, int n_in,
                              void* d_out, int out_size, void* d_ws, size_t ws_size,
                              hipStream_t stream) {
  const float* Q = (const float*)d_in[0];
  const float* S = (const float*)d_in[1];
  float* out = (float*)d_out;
  const size_t nelem = (size_t)B_ * LQ * DD;                    // 16.78M / tensor
  const size_t part_elems = (size_t)B_ * LQ * NSPLIT;
  const size_t need = 2 * nelem * sizeof(unsigned short)        // 67 MiB
                    + 3 * part_elems * sizeof(float);           // + <1 MiB

  if (ws_size >= need) {
    unsigned short* Qw = (unsigned short*)d_ws;
    unsigned short* Sw = Qw + nelem;
    float* pm   = (float*)(Sw + nelem);
    float* pse  = pm + part_elems;
    float* psel = pse + part_elems;
    int nblk = (int)(nelem / 8 / 256);   // exact: nelem divisible by 2048
    cvt_kernel<<<2 * nblk, 256, 0, stream>>>(Q, S, Qw, Sw, nblk);
    attn_kernel<<<(LQ / BQ) * B_ * NSPLIT, 512, 0, stream>>>(Qw, Sw, pm, pse, psel);
    combine_kernel<<<(B_ * LQ + 255) / 256, 256, 0, stream>>>(pm, pse, psel, out);
  } else {
    fallback_kernel<<<dim3(LQ, B_), 256, 0, stream>>>(Q, S, out);
  }
}

// Round 8
// 249.202 us; speedup vs baseline: 1.0171x; 1.0171x over previous
//
#include <hip/hip_runtime.h>
#include <hip/hip_bf16.h>

#define B_  16
#define LQ  2048
#define LS  2048
#define DD  512
#define BQ  128
#define BS  128
#define BK  64
#define NSB (LS / BS)   // 16 s-blocks total
#define NKC (DD / BK)   // 8 k-stages
#define NSPLIT 8

typedef short bf16x8 __attribute__((ext_vector_type(8)));
typedef float f32x4  __attribute__((ext_vector_type(4)));

// async global->LDS, 16B per lane. LDS dest = wave-uniform base + lane*16.
__device__ __forceinline__ void load_lds16(const void* g, void* l) {
  __builtin_amdgcn_global_load_lds((const __attribute__((address_space(1))) void*)g,
                                   (__attribute__((address_space(3))) void*)l,
                                   16, 0, 0);
}

__device__ __forceinline__ unsigned short f2bf(float f) {
  union { float f; unsigned int u; } v; v.f = f;
  unsigned int r = v.u + 0x7fffu + ((v.u >> 16) & 1u);  // RNE
  return (unsigned short)(r >> 16);
}

// Exact-size grid: blocks [0, nblk) convert Q, [nblk, 2nblk) convert S.
__global__ __launch_bounds__(256) void cvt_kernel(const float* __restrict__ Q,
                                                  const float* __restrict__ S,
                                                  unsigned short* __restrict__ Qw,
                                                  unsigned short* __restrict__ Sw,
                                                  int nblk) {
  int blk = blockIdx.x;
  const float* src; unsigned short* dst;
  if (blk < nblk) { src = Q; dst = Qw; } else { src = S; dst = Sw; blk -= nblk; }
  int i = blk * 256 + threadIdx.x;   // float4 index
  float4 f = ((const float4*)src)[i];
  ushort4 u;
  u.x = f2bf(f.x); u.y = f2bf(f.y); u.z = f2bf(f.z); u.w = f2bf(f.w);
  ((ushort4*)dst)[i] = u;
}

// score[b,q] = sum_s softmax(l)[s]*l[s],  l[s] = Q[b,q,:].S[b,s,:]
// MFMA: A = S-tile (M=s), B = Q-tile^T (N=q) -> C[row=s][col=q]
// C layout (16x16x32): col = lane&15, row = (lane>>4)*4 + reg  [m89/m91]
//
// Round-8 = round-3 structure (the 95 µs best: 512 thr, 8 waves, 128x128
// tile, 2-barrier single-buffer stage, conflict-free BK=64 XOR swizzle,
// VGPR 52) with NSPLIT 4 -> 8: grid 2048 = 8 blocks/CU nominal. r3's 39%
// occupancy (~1.5 resident blocks) was the best performer — cross-block
// overlap hides the per-stage vmcnt drain better than any intra-block
// pipelining tried (r4-r7 all matched or regressed). More blocks -> more
// overlap + smaller tail. XCD swizzle: id%8 = spl, so each XCD serves one
// S-eighth x 16 batches = 4 MB = exactly its L2.
__global__ __launch_bounds__(512, 4) void attn_kernel(const unsigned short* __restrict__ Qw,
                                                      const unsigned short* __restrict__ Sw,
                                                      float* __restrict__ pm,
                                                      float* __restrict__ pse,
                                                      float* __restrict__ psel) {
  __shared__ __align__(16) unsigned short sQ[BQ * BK];  // 16 KiB
  __shared__ __align__(16) unsigned short sS[BS * BK];  // 16 KiB

  const int id   = blockIdx.x;
  const int qb   = id >> 7;        // 0..15
  const int b    = (id >> 3) & 15; // 0..15
  const int spl  = id & 7;         // 0..7  (= XCD via id%8)
  const int tid  = threadIdx.x;
  const int w    = tid >> 6;      // 0..7
  const int lane = tid & 63;
  const int h    = w & 1;         // s-half: rows [h*64, h*64+64)
  const int g    = w >> 1;        // q-group: cols [g*32, g*32+32)
  const int col  = lane & 15;
  const int quad = lane >> 4;
  const int c7   = col & 7;

  const int q0 = qb * BQ;
  const unsigned short* Qb = Qw + (size_t)b * LQ * DD;
  const unsigned short* Sb = Sw + (size_t)b * LS * DD;

  float mst[2] = { -INFINITY, -INFINITY };
  float se[2]  = { 0.f, 0.f };
  float sel[2] = { 0.f, 0.f };

  f32x4 acc[4][2];   // [s-tile within half][q-tile] = 32 VGPRs

  const int rr    = lane >> 3;                 // row within 8-row staging unit
  const int cc    = ((lane & 7) ^ rr) * 8;     // swizzled global k-chunk
  const int srow0 = (w & 3) * 32;              // staging row base (waves 0-3: sQ, 4-7: sS)

  const int sbp = NSB / NSPLIT;                // 2 s-blocks per split
  const int sbs = spl * sbp;
  const int sbe = sbs + sbp;

  for (int sb = sbs; sb < sbe; ++sb) {
    const int s0 = sb * BS;
#pragma unroll
    for (int st = 0; st < 4; ++st)
#pragma unroll
      for (int qt = 0; qt < 2; ++qt)
        acc[st][qt] = (f32x4){0.f, 0.f, 0.f, 0.f};

    for (int kc = 0; kc < NKC; ++kc) {
      __syncthreads();  // previous stage's LDS reads complete
      if (w < 4) {
#pragma unroll
        for (int i = 0; i < 4; ++i) {
          int r = srow0 + i * 8 + rr;
          load_lds16(Qb + (size_t)(q0 + r) * DD + kc * BK + cc, &sQ[(srow0 + i * 8) * BK]);
        }
      } else {
#pragma unroll
        for (int i = 0; i < 4; ++i) {
          int r = srow0 + i * 8 + rr;
          load_lds16(Sb + (size_t)(s0 + r) * DD + kc * BK + cc, &sS[(srow0 + i * 8) * BK]);
        }
      }
      __syncthreads();  // drains vmcnt before barrier

#pragma unroll
      for (int kk = 0; kk < 2; ++kk) {
        const int koff = ((kk * 4 + quad) ^ c7) * 8;
        bf16x8 aq[2], asv[4];
#pragma unroll
        for (int qt = 0; qt < 2; ++qt)
          aq[qt] = *(const bf16x8*)&sQ[(g * 32 + qt * 16 + col) * BK + koff];
#pragma unroll
        for (int st = 0; st < 4; ++st)
          asv[st] = *(const bf16x8*)&sS[(h * 64 + st * 16 + col) * BK + koff];
#pragma unroll
        for (int st = 0; st < 4; ++st)
#pragma unroll
          for (int qt = 0; qt < 2; ++qt)
            acc[st][qt] = __builtin_amdgcn_mfma_f32_16x16x32_bf16(asv[st], aq[qt], acc[st][qt], 0, 0, 0);
      }
    }

    // online softmax-weighted-mean update over this wave's 64-s half-block
#pragma unroll
    for (int qt = 0; qt < 2; ++qt) {
      float lmax = mst[qt];
#pragma unroll
      for (int st = 0; st < 4; ++st)
#pragma unroll
        for (int r = 0; r < 4; ++r)
          lmax = fmaxf(lmax, acc[st][qt][r]);
      lmax = fmaxf(lmax, __shfl_xor(lmax, 16, 64));
      lmax = fmaxf(lmax, __shfl_xor(lmax, 32, 64));
      float alpha = __expf(mst[qt] - lmax);  // exp(-inf)=0 on first block
      float pe = 0.f, pel = 0.f;
#pragma unroll
      for (int st = 0; st < 4; ++st)
#pragma unroll
        for (int r = 0; r < 4; ++r) {
          float l = acc[st][qt][r];
          float e = __expf(l - lmax);
          pe += e;
          pel = fmaf(e, l, pel);
        }
      pe  += __shfl_xor(pe, 16, 64);  pe  += __shfl_xor(pe, 32, 64);
      pel += __shfl_xor(pel, 16, 64); pel += __shfl_xor(pel, 32, 64);
      se[qt]  = fmaf(se[qt],  alpha, pe);
      sel[qt] = fmaf(sel[qt], alpha, pel);
      mst[qt] = lmax;
    }
  }

  // merge the two s-halves (h=0,1) per q-group via LDS, write split partials
  __syncthreads();
  float* red = (float*)sQ;   // 3*256 floats = 3 KiB, sQ no longer needed
  if (quad == 0) {
#pragma unroll
    for (int qt = 0; qt < 2; ++qt) {
      int idx = ((g * 2 + h) * 2 + qt) * 16 + col;
      red[idx]       = mst[qt];
      red[256 + idx] = se[qt];
      red[512 + idx] = sel[qt];
    }
  }
  __syncthreads();
  if (h == 0 && quad == 0) {
#pragma unroll
    for (int qt = 0; qt < 2; ++qt) {
      int i0 = ((g * 2 + 0) * 2 + qt) * 16 + col;
      int i1 = ((g * 2 + 1) * 2 + qt) * 16 + col;
      float m0 = red[i0], m1 = red[i1];
      float M  = fmaxf(m0, m1);
      float a0 = __expf(m0 - M), a1 = __expf(m1 - M);
      float SE  = red[256 + i0] * a0 + red[256 + i1] * a1;
      float SEL = red[512 + i0] * a0 + red[512 + i1] * a1;
      size_t qi = (size_t)b * LQ + q0 + g * 32 + qt * 16 + col;
      pm[qi * NSPLIT + spl]   = M;
      pse[qi * NSPLIT + spl]  = SE;
      psel[qi * NSPLIT + spl] = SEL;
    }
  }
}

__global__ __launch_bounds__(256) void combine_kernel(const float* __restrict__ pm,
                                                      const float* __restrict__ pse,
                                                      const float* __restrict__ psel,
                                                      float* __restrict__ out) {
  int i = blockIdx.x * blockDim.x + threadIdx.x;
  if (i >= B_ * LQ) return;
  float M = -INFINITY;
#pragma unroll
  for (int s = 0; s < NSPLIT; ++s) M = fmaxf(M, pm[i * NSPLIT + s]);
  float SE = 0.f, SEL = 0.f;
#pragma unroll
  for (int s = 0; s < NSPLIT; ++s) {
    float a = __expf(pm[i * NSPLIT + s] - M);
    SE  = fmaf(pse[i * NSPLIT + s],  a, SE);
    SEL = fmaf(psel[i * NSPLIT + s], a, SEL);
  }
  out[i] = SEL / SE;
}

// fp32 fallback (correctness insurance if ws too small)
__global__ __launch_bounds__(256) void fallback_kernel(const float* __restrict__ Q,
                                                       const float* __restrict__ S,
                                                       float* __restrict__ out) {
  __shared__ float qv[DD];
  __shared__ float red[256];
  const int b = blockIdx.y, qi = blockIdx.x, tid = threadIdx.x;
  const float* qrow = Q + ((size_t)b * LQ + qi) * DD;
  for (int d = tid; d < DD; d += 256) qv[d] = qrow[d];
  __syncthreads();
  const float* Sb = S + (size_t)b * LS * DD;
  float m = -INFINITY, se = 0.f, sel = 0.f;
  for (int s = tid; s < LS; s += 256) {
    const float* srow = Sb + (size_t)s * DD;
    float dot = 0.f;
    for (int d = 0; d < DD; ++d) dot = fmaf(qv[d], srow[d], dot);
    float mn = fmaxf(m, dot);
    float a = __expf(m - mn);
    float e = __expf(dot - mn);
    se  = se * a + e;
    sel = sel * a + e * dot;
    m = mn;
  }
  red[tid] = m; __syncthreads();
  for (int o = 128; o > 0; o >>= 1) { if (tid < o) red[tid] = fmaxf(red[tid], red[tid + o]); __syncthreads(); }
  float M = red[0]; __syncthreads();
  float a = __expf(m - M); se *= a; sel *= a;
  red[tid] = se; __syncthreads();
  for (int o = 128; o > 0; o >>= 1) { if (tid < o) red[tid] += red[tid + o]; __syncthreads(); }
  float SE = red[0]; __syncthreads();
  red[tid] = sel; __syncthreads();
  for (int o = 128; o > 0; o >>= 1) { if (tid < o) red[tid] += red[tid + o]; __syncthreads(); }
  float SEL = red[0];
  if (tid == 0) out[(size_t)b * LQ + qi] = SEL / SE;
}

extern "C" void kernel_launch(void* const* d_in, const int* in_sizes, int n_in,
                              void* d_out, int out_size, void* d_ws, size_t ws_size,
                              hipStream_t stream) {
  const float* Q = (const float*)d_in[0];
  const float* S = (const float*)d_in[1];
  float* out = (float*)d_out;
  const size_t nelem = (size_t)B_ * LQ * DD;                    // 16.78M / tensor
  const size_t part_elems = (size_t)B_ * LQ * NSPLIT;
  const size_t need = 2 * nelem * sizeof(unsigned short)        // 67 MiB
                    + 3 * part_elems * sizeof(float);           // + 3 MiB

  if (ws_size >= need) {
    unsigned short* Qw = (unsigned short*)d_ws;
    unsigned short* Sw = Qw + nelem;
    float* pm   = (float*)(Sw + nelem);
    float* pse  = pm + part_elems;
    float* psel = pse + part_elems;
    int nblk = (int)(nelem / 4 / 256);   // exact: nelem divisible by 1024
    cvt_kernel<<<2 * nblk, 256, 0, stream>>>(Q, S, Qw, Sw, nblk);
    attn_kernel<<<(LQ / BQ) * B_ * NSPLIT, 512, 0, stream>>>(Qw, Sw, pm, pse, psel);
    combine_kernel<<<(B_ * LQ + 255) / 256, 256, 0, stream>>>(pm, pse, psel, out);
  } else {
    fallback_kernel<<<dim3(LQ, B_), 256, 0, stream>>>(Q, S, out);
  }
}